// Round 3
// baseline (1551.803 us; speedup 1.0000x reference)
//
#include <hip/hip_runtime.h>
#include <stdint.h>

typedef unsigned short u16;
typedef __attribute__((ext_vector_type(8))) short short8;   // 8 bf16 = 4 VGPRs
typedef __attribute__((ext_vector_type(4))) float floatx4;  // MFMA accumulator

#define NTOK 4096
#define DDIM 1024
#define FDIM 2048
#define NEXP 8

__device__ __forceinline__ u16 f2bf(float f) {
    union { float f; uint32_t u; } v; v.f = f;
    uint32_t r = v.u + 0x7fff + ((v.u >> 16) & 1);  // RNE
    return (u16)(r >> 16);
}
__device__ __forceinline__ uint32_t pk2(float a, float b) {
    return (uint32_t)f2bf(a) | ((uint32_t)f2bf(b) << 16);
}

// ---------------------------------------------------------------- router
// one wave per token; fp32 logits, top-2; weights = renormalized softmax pair
__global__ __launch_bounds__(256)
void router_kernel(const float* __restrict__ x, const float* __restrict__ rw,
                   int* __restrict__ counts, int* __restrict__ topk_e,
                   float* __restrict__ topk_w) {
    const int lane = threadIdx.x & 63;
    const int wv = threadIdx.x >> 6;
    const int tok = blockIdx.x * 4 + wv;
    const float* xr = x + (size_t)tok * DDIM;
    float acc[8];
#pragma unroll
    for (int e = 0; e < 8; ++e) acc[e] = 0.f;
#pragma unroll
    for (int it = 0; it < 4; ++it) {
        int d0 = (it * 64 + lane) * 4;
        float4 xv = *(const float4*)(xr + d0);
#pragma unroll
        for (int e = 0; e < 8; ++e) {
            float4 wv4 = *(const float4*)(rw + (size_t)e * DDIM + d0);
            acc[e] += xv.x * wv4.x + xv.y * wv4.y + xv.z * wv4.z + xv.w * wv4.w;
        }
    }
#pragma unroll
    for (int s = 32; s > 0; s >>= 1)
#pragma unroll
        for (int e = 0; e < 8; ++e) acc[e] += __shfl_down(acc[e], s);
    if (lane == 0) {
        int e0 = 0;
#pragma unroll
        for (int e = 1; e < 8; ++e) if (acc[e] > acc[e0]) e0 = e;
        int e1 = (e0 == 0) ? 1 : 0;
#pragma unroll
        for (int e = 0; e < 8; ++e) if (e != e0 && acc[e] > acc[e1]) e1 = e;
        // w0 = p0/(p0+p1) = 1/(1+exp(l1-l0)), l0 >= l1 -> stable, in (0.5,1]
        float w0 = 1.f / (1.f + __expf(acc[e1] - acc[e0]));
        topk_e[tok * 2 + 0] = e0;
        topk_e[tok * 2 + 1] = e1;
        topk_w[tok * 2 + 0] = w0;
        topk_w[tok * 2 + 1] = 1.f - w0;
        atomicAdd(&counts[e0], 1);
        atomicAdd(&counts[e1], 1);
    }
}

__global__ void prefix_kernel(const int* __restrict__ counts, int* __restrict__ offs,
                              int* __restrict__ cursors) {
    if (threadIdx.x == 0) {
        int s = 0;
        for (int e = 0; e < NEXP; ++e) { offs[e] = s; s += counts[e]; }
        offs[NEXP] = s;
    }
    if (threadIdx.x < NEXP) cursors[threadIdx.x] = 0;
}

__global__ __launch_bounds__(256)
void build_rows(const int* __restrict__ topk_e, const int* __restrict__ offs,
                int* __restrict__ cursors, int* __restrict__ row_tok,
                float* __restrict__ gate_row, const float* __restrict__ topk_w) {
    int tok = blockIdx.x * 256 + threadIdx.x;
#pragma unroll
    for (int k = 0; k < 2; ++k) {
        int e = topk_e[tok * 2 + k];
        int slot = atomicAdd(&cursors[e], 1);
        int row = offs[e] + slot;
        row_tok[row] = tok;
        gate_row[row] = topk_w[tok * 2 + k];
    }
}

// ---------------------------------------------------------------- GEMM1 + SwiGLU
// gathered X[rows,1024](fp32) @ w1[e] ([D=1024][2F=4096] fp32, k-major)
// -> act(bf16) = silu(g)*h.  tile: 128 rows x 64 gh-cols, BK=32.
__global__ __launch_bounds__(256, 2)
void gemm1_kernel(const float* __restrict__ x, const float* __restrict__ w1,
                  u16* __restrict__ act, const int* __restrict__ row_tok,
                  const int* __restrict__ counts, const int* __restrict__ offs) {
    const int e = blockIdx.z;
    const int cnt = counts[e];
    const int m0 = blockIdx.x * 128;
    if (m0 >= cnt) return;
    const int off = offs[e];
    const int n0 = blockIdx.y * 64;

    __shared__ __align__(16) u16 As[4 * 128 * 8];  // [kc][m][8]: A[m][k0+kc*8+j]
    __shared__ __align__(16) u16 Bg[4 * 64 * 8];   // [kc][n][j]: B[k0+kc*8+j][n0+n]
    __shared__ __align__(16) u16 Bh[4 * 64 * 8];

    const int t = threadIdx.x;
    const int lane = t & 63;
    const int wv = t >> 6;
    const int quad = lane >> 4;
    const int rr = lane & 15;
    const int wm = wv * 32;   // wave's 32-row strip of the 128-row tile

    // A staging: 2 slots (8 fp32 each) per thread
    const float* aptr[2];
    int asl[2];
#pragma unroll
    for (int it = 0; it < 2; ++it) {
        int u = it * 256 + t;
        int am = u & 127;
        int akc = u >> 7;  // 0..3
        int r = m0 + am; if (r >= cnt) r = cnt - 1;  // clamp tail; stores masked
        aptr[it] = x + (size_t)row_tok[off + r] * DDIM + akc * 8;
        asl[it] = (akc * 128 + am) * 8;
    }
    // B staging: thread t loads k=bk, n=bn..bn+8 of each of g,h
    const int bk = t >> 3;        // 0..31
    const int bn = (t & 7) * 8;   // 0..56
    const float* gptr = w1 + (size_t)e * DDIM * (2 * FDIM) + (size_t)bk * (2 * FDIM) + (n0 + bn);
    const float* hptr = gptr + FDIM;
    const int bsl = ((bk >> 3) * 64 + bn) * 8 + (bk & 7);

    floatx4 accg[2][4] = {};
    floatx4 acch[2][4] = {};

    for (int k0 = 0; k0 < DDIM; k0 += 32) {
        float4 a00 = *(const float4*)(aptr[0] + k0);
        float4 a01 = *(const float4*)(aptr[0] + k0 + 4);
        float4 a10 = *(const float4*)(aptr[1] + k0);
        float4 a11 = *(const float4*)(aptr[1] + k0 + 4);
        const float* gk = gptr + (size_t)k0 * (2 * FDIM);
        float4 g0 = *(const float4*)(gk);
        float4 g1 = *(const float4*)(gk + 4);
        const float* hk = hptr + (size_t)k0 * (2 * FDIM);
        float4 h0 = *(const float4*)(hk);
        float4 h1 = *(const float4*)(hk + 4);
        __syncthreads();  // previous iteration's LDS reads complete
        {
            uint4 v0 = { pk2(a00.x, a00.y), pk2(a00.z, a00.w), pk2(a01.x, a01.y), pk2(a01.z, a01.w) };
            *(uint4*)&As[asl[0]] = v0;
            uint4 v1 = { pk2(a10.x, a10.y), pk2(a10.z, a10.w), pk2(a11.x, a11.y), pk2(a11.z, a11.w) };
            *(uint4*)&As[asl[1]] = v1;
        }
        {
            float gs[8] = { g0.x, g0.y, g0.z, g0.w, g1.x, g1.y, g1.z, g1.w };
            float hs[8] = { h0.x, h0.y, h0.z, h0.w, h1.x, h1.y, h1.z, h1.w };
#pragma unroll
            for (int j = 0; j < 8; ++j) {
                Bg[bsl + j * 8] = f2bf(gs[j]);
                Bh[bsl + j * 8] = f2bf(hs[j]);
            }
        }
        __syncthreads();

        short8 af[2];
        af[0] = *(const short8*)&As[(quad * 128 + wm + rr) * 8];
        af[1] = *(const short8*)&As[(quad * 128 + wm + 16 + rr) * 8];
#pragma unroll
        for (int nt = 0; nt < 4; ++nt) {
            short8 bg = *(const short8*)&Bg[(quad * 64 + nt * 16 + rr) * 8];
            short8 bh = *(const short8*)&Bh[(quad * 64 + nt * 16 + rr) * 8];
#pragma unroll
            for (int mt = 0; mt < 2; ++mt) {
                accg[mt][nt] = __builtin_amdgcn_mfma_f32_16x16x32_bf16(af[mt], bg, accg[mt][nt], 0, 0, 0);
                acch[mt][nt] = __builtin_amdgcn_mfma_f32_16x16x32_bf16(af[mt], bh, acch[mt][nt], 0, 0, 0);
            }
        }
    }
    // epilogue: C/D layout col=lane&15, row=quad*4+reg
#pragma unroll
    for (int mt = 0; mt < 2; ++mt)
#pragma unroll
        for (int nt = 0; nt < 4; ++nt)
#pragma unroll
            for (int rg = 0; rg < 4; ++rg) {
                int gm = m0 + wm + mt * 16 + quad * 4 + rg;
                if (gm < cnt) {
                    float g = accg[mt][nt][rg];
                    float h = acch[mt][nt][rg];
                    float s = g / (1.f + __expf(-g));
                    act[(size_t)(off + gm) * FDIM + (n0 + nt * 16 + rr)] = f2bf(s * h);
                }
            }
}

// ---------------------------------------------------------------- GEMM2 + scatter-combine
// act[rows,2048](bf16) @ w2[e] ([F=2048][D=1024] fp32, k-major)
// -> out[tok] += gate * y   (fp32 atomics; out pre-zeroed)
__global__ __launch_bounds__(256, 2)
void gemm2_kernel(const u16* __restrict__ act, const float* __restrict__ w2,
                  float* __restrict__ out, const int* __restrict__ row_tok,
                  const float* __restrict__ gate_row, const int* __restrict__ counts,
                  const int* __restrict__ offs) {
    const int e = blockIdx.z;
    const int cnt = counts[e];
    const int m0 = blockIdx.x * 128;
    if (m0 >= cnt) return;
    const int off = offs[e];
    const int n0 = blockIdx.y * 64;

    __shared__ __align__(16) u16 As[4 * 128 * 8];
    __shared__ __align__(16) u16 Bs[4 * 64 * 8];

    const int t = threadIdx.x;
    const int lane = t & 63;
    const int wv = t >> 6;
    const int quad = lane >> 4;
    const int rr = lane & 15;
    const int wm = wv * 32;

    const u16* aptr[2];
    int asl[2];
#pragma unroll
    for (int it = 0; it < 2; ++it) {
        int u = it * 256 + t;
        int am = u & 127;
        int akc = u >> 7;
        int r = m0 + am; if (r >= cnt) r = cnt - 1;
        aptr[it] = act + (size_t)(off + r) * FDIM + akc * 8;
        asl[it] = (akc * 128 + am) * 8;
    }
    const int bk = t >> 3;
    const int bn = (t & 7) * 8;
    const float* bptr = w2 + (size_t)e * FDIM * DDIM + (size_t)bk * DDIM + (n0 + bn);
    const int bsl = ((bk >> 3) * 64 + bn) * 8 + (bk & 7);

    floatx4 acc[2][4] = {};

    for (int k0 = 0; k0 < FDIM; k0 += 32) {
        uint4 av0 = *(const uint4*)(aptr[0] + k0);
        uint4 av1 = *(const uint4*)(aptr[1] + k0);
        const float* bkp = bptr + (size_t)k0 * DDIM;
        float4 b0 = *(const float4*)(bkp);
        float4 b1 = *(const float4*)(bkp + 4);
        __syncthreads();
        *(uint4*)&As[asl[0]] = av0;
        *(uint4*)&As[asl[1]] = av1;
        {
            float bs[8] = { b0.x, b0.y, b0.z, b0.w, b1.x, b1.y, b1.z, b1.w };
#pragma unroll
            for (int j = 0; j < 8; ++j) Bs[bsl + j * 8] = f2bf(bs[j]);
        }
        __syncthreads();

        short8 af[2];
        af[0] = *(const short8*)&As[(quad * 128 + wm + rr) * 8];
        af[1] = *(const short8*)&As[(quad * 128 + wm + 16 + rr) * 8];
#pragma unroll
        for (int nt = 0; nt < 4; ++nt) {
            short8 bf = *(const short8*)&Bs[(quad * 64 + nt * 16 + rr) * 8];
#pragma unroll
            for (int mt = 0; mt < 2; ++mt)
                acc[mt][nt] = __builtin_amdgcn_mfma_f32_16x16x32_bf16(af[mt], bf, acc[mt][nt], 0, 0, 0);
        }
    }
#pragma unroll
    for (int mt = 0; mt < 2; ++mt)
#pragma unroll
        for (int rg = 0; rg < 4; ++rg) {
            int gm = m0 + wm + mt * 16 + quad * 4 + rg;
            if (gm < cnt) {
                int gr = off + gm;
                int tok = row_tok[gr];
                float gate = gate_row[gr];
                float* orow = out + (size_t)tok * DDIM + n0;
#pragma unroll
                for (int nt = 0; nt < 4; ++nt)
                    atomicAdd(&orow[nt * 16 + rr], gate * acc[mt][nt][rg]);
            }
        }
}

// ---------------------------------------------------------------- launch
extern "C" void kernel_launch(void* const* d_in, const int* in_sizes, int n_in,
                              void* d_out, int out_size, void* d_ws, size_t ws_size,
                              hipStream_t stream) {
    const float* x  = (const float*)d_in[0];  // [4096][1024] fp32
    const float* rw = (const float*)d_in[1];  // [8][1024]
    const float* w1 = (const float*)d_in[2];  // [8][1024][4096] (k-major)
    const float* w2 = (const float*)d_in[3];  // [8][2048][1024] (k-major)
    float* out = (float*)d_out;               // [4096][1024] fp32

    char* ws = (char*)d_ws;
    const size_t MB = 1ull << 20;
    // meta < 1 MiB, act 32 MiB -> 33 MiB total ws use
    int*   counts   = (int*)(ws);
    int*   cursors  = (int*)(ws + 64);
    int*   offs     = (int*)(ws + 128);
    int*   topk_e   = (int*)(ws + 1024);                  // 8192 ints
    float* topk_w   = (float*)(ws + 1024 + 4 * 8192);     // 8192 floats
    int*   row_tok  = (int*)(ws + 1024 + 8 * 8192);       // 8192 ints
    float* gate_row = (float*)(ws + 1024 + 12 * 8192);    // 8192 floats
    u16*   act      = (u16*)(ws + 1 * MB);                // [8192][2048] bf16

    hipMemsetAsync(counts, 0, 128, stream);               // counts + cursors
    hipMemsetAsync(out, 0, (size_t)out_size * 4, stream); // fp32 accumulation target
    router_kernel<<<dim3(NTOK / 4), 256, 0, stream>>>(x, rw, counts, topk_e, topk_w);
    prefix_kernel<<<1, 64, 0, stream>>>(counts, offs, cursors);
    build_rows<<<dim3(NTOK / 256), 256, 0, stream>>>(topk_e, offs, cursors, row_tok, gate_row, topk_w);
    gemm1_kernel<<<dim3(NTOK / 128, FDIM / 64, NEXP), 256, 0, stream>>>(x, w1, act, row_tok, counts, offs);
    gemm2_kernel<<<dim3(NTOK / 128, DDIM / 64, NEXP), 256, 0, stream>>>(act, w2, out, row_tok, gate_row, counts, offs);
    (void)in_sizes; (void)n_in; (void)ws_size;
}

// Round 4
// 1190.743 us; speedup vs baseline: 1.3032x; 1.3032x over previous
//
#include <hip/hip_runtime.h>
#include <stdint.h>

typedef unsigned short u16;
typedef __attribute__((ext_vector_type(8))) short short8;   // 8 bf16 = 4 VGPRs
typedef __attribute__((ext_vector_type(4))) float floatx4;  // MFMA accumulator

#define NTOK 4096
#define DDIM 1024
#define FDIM 2048
#define NEXP 8

__device__ __forceinline__ u16 f2bf(float f) {
    union { float f; uint32_t u; } v; v.f = f;
    uint32_t r = v.u + 0x7fff + ((v.u >> 16) & 1);  // RNE
    return (u16)(r >> 16);
}
__device__ __forceinline__ uint32_t pk2(float a, float b) {
    return (uint32_t)f2bf(a) | ((uint32_t)f2bf(b) << 16);
}
// async global->LDS, 16B per lane; LDS dest is wave-uniform base + lane*16
__device__ __forceinline__ void gl_lds16(const u16* g, u16* l) {
    __builtin_amdgcn_global_load_lds(
        (const __attribute__((address_space(1))) uint32_t*)g,
        (__attribute__((address_space(3))) uint32_t*)l, 16, 0, 0);
}

// ---------------------------------------------------------------- router
__global__ __launch_bounds__(256)
void router_kernel(const float* __restrict__ x, const float* __restrict__ rw,
                   int* __restrict__ counts, int* __restrict__ topk_e,
                   float* __restrict__ topk_w) {
    const int lane = threadIdx.x & 63;
    const int wv = threadIdx.x >> 6;
    const int tok = blockIdx.x * 4 + wv;
    const float* xr = x + (size_t)tok * DDIM;
    float acc[8];
#pragma unroll
    for (int e = 0; e < 8; ++e) acc[e] = 0.f;
#pragma unroll
    for (int it = 0; it < 4; ++it) {
        int d0 = (it * 64 + lane) * 4;
        float4 xv = *(const float4*)(xr + d0);
#pragma unroll
        for (int e = 0; e < 8; ++e) {
            float4 wv4 = *(const float4*)(rw + (size_t)e * DDIM + d0);
            acc[e] += xv.x * wv4.x + xv.y * wv4.y + xv.z * wv4.z + xv.w * wv4.w;
        }
    }
#pragma unroll
    for (int s = 32; s > 0; s >>= 1)
#pragma unroll
        for (int e = 0; e < 8; ++e) acc[e] += __shfl_down(acc[e], s);
    if (lane == 0) {
        int e0 = 0;
#pragma unroll
        for (int e = 1; e < 8; ++e) if (acc[e] > acc[e0]) e0 = e;
        int e1 = (e0 == 0) ? 1 : 0;
#pragma unroll
        for (int e = 0; e < 8; ++e) if (e != e0 && acc[e] > acc[e1]) e1 = e;
        float w0 = 1.f / (1.f + __expf(acc[e1] - acc[e0]));
        topk_e[tok * 2 + 0] = e0;
        topk_e[tok * 2 + 1] = e1;
        topk_w[tok * 2 + 0] = w0;
        topk_w[tok * 2 + 1] = 1.f - w0;
        atomicAdd(&counts[e0], 1);
        atomicAdd(&counts[e1], 1);
    }
}

__global__ void prefix_kernel(const int* __restrict__ counts, int* __restrict__ offs,
                              int* __restrict__ cursors) {
    if (threadIdx.x == 0) {
        int s = 0;
        for (int e = 0; e < NEXP; ++e) { offs[e] = s; s += counts[e]; }
        offs[NEXP] = s;
    }
    if (threadIdx.x < NEXP) cursors[threadIdx.x] = 0;
}

__global__ __launch_bounds__(256)
void build_rows(const int* __restrict__ topk_e, const int* __restrict__ offs,
                int* __restrict__ cursors, int* __restrict__ row_tok,
                float* __restrict__ gate_row, const float* __restrict__ topk_w) {
    int tok = blockIdx.x * 256 + threadIdx.x;
#pragma unroll
    for (int k = 0; k < 2; ++k) {
        int e = topk_e[tok * 2 + k];
        int slot = atomicAdd(&cursors[e], 1);
        int row = offs[e] + slot;
        row_tok[row] = tok;
        gate_row[row] = topk_w[tok * 2 + k];
    }
}

// ---------------------------------------------------------------- prep passes
// fp32 -> bf16, straight copy (x)
__global__ __launch_bounds__(256)
void convert_x(const float* __restrict__ src, u16* __restrict__ dst) {
    size_t i = ((size_t)blockIdx.x * 256 + threadIdx.x) * 8;
    float4 a = *(const float4*)(src + i);
    float4 b = *(const float4*)(src + i + 4);
    uint4 o = { pk2(a.x, a.y), pk2(a.z, a.w), pk2(b.x, b.y), pk2(b.z, b.w) };
    *(uint4*)(dst + i) = o;
}

// per-expert [R][C] fp32 -> [C][R] bf16, 64x64 LDS tiles. grid (C/64, R/64, E)
__global__ __launch_bounds__(256)
void transpose_f32_bf16(const float* __restrict__ src, u16* __restrict__ dst,
                        int R, int C) {
    __shared__ float tile[64][65];  // +1 pad: 2-way max on both phases
    size_t eo = (size_t)blockIdx.z * R * C;
    const float* S = src + eo;
    u16* D = dst + eo;
    int r0 = blockIdx.y * 64, c0 = blockIdx.x * 64;
    int t = threadIdx.x;
    int rr = t >> 4;          // 0..15
    int cc = (t & 15) * 4;    // 0..60
#pragma unroll
    for (int it = 0; it < 4; ++it) {
        int r = rr + it * 16;
        float4 v = *(const float4*)(S + (size_t)(r0 + r) * C + (c0 + cc));
        tile[cc + 0][r] = v.x; tile[cc + 1][r] = v.y;
        tile[cc + 2][r] = v.z; tile[cc + 3][r] = v.w;
    }
    __syncthreads();
#pragma unroll
    for (int it = 0; it < 2; ++it) {
        int u = it * 256 + t;
        int c = u >> 3;         // 0..63
        int rv = (u & 7) * 8;   // 0..56
        uint4 o;
        o.x = pk2(tile[c][rv + 0], tile[c][rv + 1]);
        o.y = pk2(tile[c][rv + 2], tile[c][rv + 3]);
        o.z = pk2(tile[c][rv + 4], tile[c][rv + 5]);
        o.w = pk2(tile[c][rv + 6], tile[c][rv + 7]);
        *(uint4*)(D + (size_t)(c0 + c) * R + (r0 + rv)) = o;
    }
}

// ---------------------------------------------------------------- fast GEMM1 + SwiGLU
// xb rows (gathered) @ w1b[e] ([4096][1024] bf16, n-major/k-contig) -> act bf16
// tile 128m x 64n (g and h), BK=32, m97-style global_load_lds staging
__global__ __launch_bounds__(256, 2)
void gemm1_fast(const u16* __restrict__ xb, const u16* __restrict__ w1b,
                u16* __restrict__ act, const int* __restrict__ row_tok,
                const int* __restrict__ counts, const int* __restrict__ offs) {
    const int e = blockIdx.z;
    const int cnt = counts[e];
    const int m0 = blockIdx.x * 128;
    if (m0 >= cnt) return;
    const int off = offs[e];
    const int n0 = blockIdx.y * 64;

    __shared__ __align__(16) u16 As[4 * 128 * 8];   // [kc][m][8]
    __shared__ __align__(16) u16 Bgs[4 * 64 * 8];   // [kc][n][8]
    __shared__ __align__(16) u16 Bhs[4 * 64 * 8];

    const int t = threadIdx.x;
    const int lane = t & 63;
    const int wv = t >> 6;
    const int quad = lane >> 4;
    const int rr = lane & 15;
    const int wm = (wv & 1) * 64;
    const int wn = (wv >> 1) * 32;

    int ra = m0 + lane;      if (ra >= cnt) ra = cnt - 1;
    int rb = m0 + 64 + lane; if (rb >= cnt) rb = cnt - 1;
    const u16* a0 = xb + (size_t)row_tok[off + ra] * DDIM;
    const u16* a1 = xb + (size_t)row_tok[off + rb] * DDIM;
    const u16* bg = w1b + ((size_t)e * 4096 + n0 + lane) * DDIM;
    const u16* bh = w1b + ((size_t)e * 4096 + 2048 + n0 + lane) * DDIM;
    u16* As0 = &As[(wv * 128) * 8];
    u16* As1 = &As[(wv * 128 + 64) * 8];
    u16* Bg0 = &Bgs[(wv * 64) * 8];
    u16* Bh0 = &Bhs[(wv * 64) * 8];

    floatx4 accg[4][2] = {};
    floatx4 acch[4][2] = {};

    for (int k0 = 0; k0 < DDIM; k0 += 32) {
        __syncthreads();                 // prior ds_reads done before overwrite
        gl_lds16(a0 + k0 + wv * 8, As0);
        gl_lds16(a1 + k0 + wv * 8, As1);
        gl_lds16(bg + k0 + wv * 8, Bg0);
        gl_lds16(bh + k0 + wv * 8, Bh0);
        __syncthreads();                 // compiler drains vmcnt before barrier

        short8 af[4], bgf[2], bhf[2];
#pragma unroll
        for (int mt = 0; mt < 4; ++mt)
            af[mt] = *(const short8*)&As[(quad * 128 + wm + mt * 16 + rr) * 8];
#pragma unroll
        for (int nt = 0; nt < 2; ++nt) {
            bgf[nt] = *(const short8*)&Bgs[(quad * 64 + wn + nt * 16 + rr) * 8];
            bhf[nt] = *(const short8*)&Bhs[(quad * 64 + wn + nt * 16 + rr) * 8];
        }
#pragma unroll
        for (int mt = 0; mt < 4; ++mt)
#pragma unroll
            for (int nt = 0; nt < 2; ++nt) {
                accg[mt][nt] = __builtin_amdgcn_mfma_f32_16x16x32_bf16(af[mt], bgf[nt], accg[mt][nt], 0, 0, 0);
                acch[mt][nt] = __builtin_amdgcn_mfma_f32_16x16x32_bf16(af[mt], bhf[nt], acch[mt][nt], 0, 0, 0);
            }
    }
#pragma unroll
    for (int mt = 0; mt < 4; ++mt)
#pragma unroll
        for (int nt = 0; nt < 2; ++nt)
#pragma unroll
            for (int rg = 0; rg < 4; ++rg) {
                int gm = m0 + wm + mt * 16 + quad * 4 + rg;
                if (gm < cnt) {
                    float g = accg[mt][nt][rg];
                    float h = acch[mt][nt][rg];
                    float s = g / (1.f + __expf(-g));
                    act[(size_t)(off + gm) * FDIM + (n0 + wn + nt * 16 + rr)] = f2bf(s * h);
                }
            }
}

// ---------------------------------------------------------------- fast GEMM2 + scatter
// act @ w2b[e] ([1024][2048] bf16, n-major/k-contig) -> out += gate*y (atomics)
// tile 128m x 128n, BK=32
__global__ __launch_bounds__(256, 2)
void gemm2_fast(const u16* __restrict__ act, const u16* __restrict__ w2b,
                float* __restrict__ out, const int* __restrict__ row_tok,
                const float* __restrict__ gate_row, const int* __restrict__ counts,
                const int* __restrict__ offs) {
    const int e = blockIdx.z;
    const int cnt = counts[e];
    const int m0 = blockIdx.x * 128;
    if (m0 >= cnt) return;
    const int off = offs[e];
    const int n0 = blockIdx.y * 128;

    __shared__ __align__(16) u16 As[4 * 128 * 8];
    __shared__ __align__(16) u16 Bs[4 * 128 * 8];

    const int t = threadIdx.x;
    const int lane = t & 63;
    const int wv = t >> 6;
    const int quad = lane >> 4;
    const int rr = lane & 15;
    const int wm = (wv & 1) * 64;
    const int wn = (wv >> 1) * 64;

    int ra = m0 + lane;      if (ra >= cnt) ra = cnt - 1;
    int rb = m0 + 64 + lane; if (rb >= cnt) rb = cnt - 1;
    const u16* a0 = act + (size_t)(off + ra) * FDIM;
    const u16* a1 = act + (size_t)(off + rb) * FDIM;
    const u16* b0 = w2b + ((size_t)e * 1024 + n0 + lane) * FDIM;
    const u16* b1 = w2b + ((size_t)e * 1024 + n0 + 64 + lane) * FDIM;
    u16* As0 = &As[(wv * 128) * 8];
    u16* As1 = &As[(wv * 128 + 64) * 8];
    u16* Bs0 = &Bs[(wv * 128) * 8];
    u16* Bs1 = &Bs[(wv * 128 + 64) * 8];

    floatx4 acc[4][4] = {};

    for (int k0 = 0; k0 < FDIM; k0 += 32) {
        __syncthreads();
        gl_lds16(a0 + k0 + wv * 8, As0);
        gl_lds16(a1 + k0 + wv * 8, As1);
        gl_lds16(b0 + k0 + wv * 8, Bs0);
        gl_lds16(b1 + k0 + wv * 8, Bs1);
        __syncthreads();

        short8 af[4], bf[4];
#pragma unroll
        for (int mt = 0; mt < 4; ++mt)
            af[mt] = *(const short8*)&As[(quad * 128 + wm + mt * 16 + rr) * 8];
#pragma unroll
        for (int nt = 0; nt < 4; ++nt)
            bf[nt] = *(const short8*)&Bs[(quad * 128 + wn + nt * 16 + rr) * 8];
#pragma unroll
        for (int mt = 0; mt < 4; ++mt)
#pragma unroll
            for (int nt = 0; nt < 4; ++nt)
                acc[mt][nt] = __builtin_amdgcn_mfma_f32_16x16x32_bf16(af[mt], bf[nt], acc[mt][nt], 0, 0, 0);
    }
#pragma unroll
    for (int mt = 0; mt < 4; ++mt)
#pragma unroll
        for (int rg = 0; rg < 4; ++rg) {
            int gm = m0 + wm + mt * 16 + quad * 4 + rg;
            if (gm < cnt) {
                int gr = off + gm;
                float gate = gate_row[gr];
                float* orow = out + (size_t)row_tok[gr] * DDIM + n0 + wn;
#pragma unroll
                for (int nt = 0; nt < 4; ++nt)
                    atomicAdd(&orow[nt * 16 + rr], gate * acc[mt][nt][rg]);
            }
        }
}

// ---------------------------------------------------------------- fallback GEMMs (round-3, proven)
__global__ __launch_bounds__(256, 2)
void gemm1_kernel(const float* __restrict__ x, const float* __restrict__ w1,
                  u16* __restrict__ act, const int* __restrict__ row_tok,
                  const int* __restrict__ counts, const int* __restrict__ offs) {
    const int e = blockIdx.z;
    const int cnt = counts[e];
    const int m0 = blockIdx.x * 128;
    if (m0 >= cnt) return;
    const int off = offs[e];
    const int n0 = blockIdx.y * 64;
    __shared__ __align__(16) u16 As[4 * 128 * 8];
    __shared__ __align__(16) u16 Bg[4 * 64 * 8];
    __shared__ __align__(16) u16 Bh[4 * 64 * 8];
    const int t = threadIdx.x;
    const int lane = t & 63;
    const int wv = t >> 6;
    const int quad = lane >> 4;
    const int rr = lane & 15;
    const int wm = wv * 32;
    const float* aptr[2];
    int asl[2];
#pragma unroll
    for (int it = 0; it < 2; ++it) {
        int u = it * 256 + t;
        int am = u & 127;
        int akc = u >> 7;
        int r = m0 + am; if (r >= cnt) r = cnt - 1;
        aptr[it] = x + (size_t)row_tok[off + r] * DDIM + akc * 8;
        asl[it] = (akc * 128 + am) * 8;
    }
    const int bk = t >> 3;
    const int bn = (t & 7) * 8;
    const float* gptr = w1 + (size_t)e * DDIM * (2 * FDIM) + (size_t)bk * (2 * FDIM) + (n0 + bn);
    const float* hptr = gptr + FDIM;
    const int bsl = ((bk >> 3) * 64 + bn) * 8 + (bk & 7);
    floatx4 accg[2][4] = {};
    floatx4 acch[2][4] = {};
    for (int k0 = 0; k0 < DDIM; k0 += 32) {
        float4 a00 = *(const float4*)(aptr[0] + k0);
        float4 a01 = *(const float4*)(aptr[0] + k0 + 4);
        float4 a10 = *(const float4*)(aptr[1] + k0);
        float4 a11 = *(const float4*)(aptr[1] + k0 + 4);
        const float* gk = gptr + (size_t)k0 * (2 * FDIM);
        float4 g0 = *(const float4*)(gk);
        float4 g1 = *(const float4*)(gk + 4);
        const float* hk = hptr + (size_t)k0 * (2 * FDIM);
        float4 h0 = *(const float4*)(hk);
        float4 h1 = *(const float4*)(hk + 4);
        __syncthreads();
        {
            uint4 v0 = { pk2(a00.x, a00.y), pk2(a00.z, a00.w), pk2(a01.x, a01.y), pk2(a01.z, a01.w) };
            *(uint4*)&As[asl[0]] = v0;
            uint4 v1 = { pk2(a10.x, a10.y), pk2(a10.z, a10.w), pk2(a11.x, a11.y), pk2(a11.z, a11.w) };
            *(uint4*)&As[asl[1]] = v1;
        }
        {
            float gs[8] = { g0.x, g0.y, g0.z, g0.w, g1.x, g1.y, g1.z, g1.w };
            float hs[8] = { h0.x, h0.y, h0.z, h0.w, h1.x, h1.y, h1.z, h1.w };
#pragma unroll
            for (int j = 0; j < 8; ++j) {
                Bg[bsl + j * 8] = f2bf(gs[j]);
                Bh[bsl + j * 8] = f2bf(hs[j]);
            }
        }
        __syncthreads();
        short8 af[2];
        af[0] = *(const short8*)&As[(quad * 128 + wm + rr) * 8];
        af[1] = *(const short8*)&As[(quad * 128 + wm + 16 + rr) * 8];
#pragma unroll
        for (int nt = 0; nt < 4; ++nt) {
            short8 bg = *(const short8*)&Bg[(quad * 64 + nt * 16 + rr) * 8];
            short8 bh = *(const short8*)&Bh[(quad * 64 + nt * 16 + rr) * 8];
#pragma unroll
            for (int mt = 0; mt < 2; ++mt) {
                accg[mt][nt] = __builtin_amdgcn_mfma_f32_16x16x32_bf16(af[mt], bg, accg[mt][nt], 0, 0, 0);
                acch[mt][nt] = __builtin_amdgcn_mfma_f32_16x16x32_bf16(af[mt], bh, acch[mt][nt], 0, 0, 0);
            }
        }
    }
#pragma unroll
    for (int mt = 0; mt < 2; ++mt)
#pragma unroll
        for (int nt = 0; nt < 4; ++nt)
#pragma unroll
            for (int rg = 0; rg < 4; ++rg) {
                int gm = m0 + wm + mt * 16 + quad * 4 + rg;
                if (gm < cnt) {
                    float g = accg[mt][nt][rg];
                    float h = acch[mt][nt][rg];
                    float s = g / (1.f + __expf(-g));
                    act[(size_t)(off + gm) * FDIM + (n0 + nt * 16 + rr)] = f2bf(s * h);
                }
            }
}

__global__ __launch_bounds__(256, 2)
void gemm2_kernel(const u16* __restrict__ act, const float* __restrict__ w2,
                  float* __restrict__ out, const int* __restrict__ row_tok,
                  const float* __restrict__ gate_row, const int* __restrict__ counts,
                  const int* __restrict__ offs) {
    const int e = blockIdx.z;
    const int cnt = counts[e];
    const int m0 = blockIdx.x * 128;
    if (m0 >= cnt) return;
    const int off = offs[e];
    const int n0 = blockIdx.y * 64;
    __shared__ __align__(16) u16 As[4 * 128 * 8];
    __shared__ __align__(16) u16 Bs[4 * 64 * 8];
    const int t = threadIdx.x;
    const int lane = t & 63;
    const int wv = t >> 6;
    const int quad = lane >> 4;
    const int rr = lane & 15;
    const int wm = wv * 32;
    const u16* aptr[2];
    int asl[2];
#pragma unroll
    for (int it = 0; it < 2; ++it) {
        int u = it * 256 + t;
        int am = u & 127;
        int akc = u >> 7;
        int r = m0 + am; if (r >= cnt) r = cnt - 1;
        aptr[it] = act + (size_t)(off + r) * FDIM + akc * 8;
        asl[it] = (akc * 128 + am) * 8;
    }
    const int bk = t >> 3;
    const int bn = (t & 7) * 8;
    const float* bptr = w2 + (size_t)e * FDIM * DDIM + (size_t)bk * DDIM + (n0 + bn);
    const int bsl = ((bk >> 3) * 64 + bn) * 8 + (bk & 7);
    floatx4 acc[2][4] = {};
    for (int k0 = 0; k0 < FDIM; k0 += 32) {
        uint4 av0 = *(const uint4*)(aptr[0] + k0);
        uint4 av1 = *(const uint4*)(aptr[1] + k0);
        const float* bkp = bptr + (size_t)k0 * DDIM;
        float4 b0 = *(const float4*)(bkp);
        float4 b1 = *(const float4*)(bkp + 4);
        __syncthreads();
        *(uint4*)&As[asl[0]] = av0;
        *(uint4*)&As[asl[1]] = av1;
        {
            float bs[8] = { b0.x, b0.y, b0.z, b0.w, b1.x, b1.y, b1.z, b1.w };
#pragma unroll
            for (int j = 0; j < 8; ++j) Bs[bsl + j * 8] = f2bf(bs[j]);
        }
        __syncthreads();
        short8 af[2];
        af[0] = *(const short8*)&As[(quad * 128 + wm + rr) * 8];
        af[1] = *(const short8*)&As[(quad * 128 + wm + 16 + rr) * 8];
#pragma unroll
        for (int nt = 0; nt < 4; ++nt) {
            short8 bf = *(const short8*)&Bs[(quad * 64 + nt * 16 + rr) * 8];
#pragma unroll
            for (int mt = 0; mt < 2; ++mt)
                acc[mt][nt] = __builtin_amdgcn_mfma_f32_16x16x32_bf16(af[mt], bf, acc[mt][nt], 0, 0, 0);
        }
    }
#pragma unroll
    for (int mt = 0; mt < 2; ++mt)
#pragma unroll
        for (int rg = 0; rg < 4; ++rg) {
            int gm = m0 + wm + mt * 16 + quad * 4 + rg;
            if (gm < cnt) {
                int gr = off + gm;
                float gate = gate_row[gr];
                float* orow = out + (size_t)row_tok[gr] * DDIM + n0;
#pragma unroll
                for (int nt = 0; nt < 4; ++nt)
                    atomicAdd(&orow[nt * 16 + rr], gate * acc[mt][nt][rg]);
            }
        }
}

// ---------------------------------------------------------------- launch
extern "C" void kernel_launch(void* const* d_in, const int* in_sizes, int n_in,
                              void* d_out, int out_size, void* d_ws, size_t ws_size,
                              hipStream_t stream) {
    const float* x  = (const float*)d_in[0];  // [4096][1024]
    const float* rw = (const float*)d_in[1];  // [8][1024]
    const float* w1 = (const float*)d_in[2];  // [8][1024][4096] k-major
    const float* w2 = (const float*)d_in[3];  // [8][2048][1024] k-major
    float* out = (float*)d_out;               // [4096][1024]

    char* ws = (char*)d_ws;
    const size_t MB = 1ull << 20;
    int*   counts   = (int*)(ws);
    int*   cursors  = (int*)(ws + 64);
    int*   offs     = (int*)(ws + 128);
    int*   topk_e   = (int*)(ws + 1024);
    float* topk_w   = (float*)(ws + 1024 + 4 * 8192);
    int*   row_tok  = (int*)(ws + 1024 + 8 * 8192);
    float* gate_row = (float*)(ws + 1024 + 12 * 8192);
    u16*   act      = (u16*)(ws + 1 * MB);    // 32 MiB
    u16*   xb       = (u16*)(ws + 33 * MB);   // 8 MiB
    u16*   w1b      = (u16*)(ws + 41 * MB);   // 64 MiB (alive through gemm1)
    u16*   w2b      = (u16*)(ws + 41 * MB);   // 32 MiB overlay (after gemm1)

    hipMemsetAsync(counts, 0, 128, stream);
    hipMemsetAsync(out, 0, (size_t)out_size * 4, stream);
    router_kernel<<<dim3(NTOK / 4), 256, 0, stream>>>(x, rw, counts, topk_e, topk_w);
    prefix_kernel<<<1, 64, 0, stream>>>(counts, offs, cursors);
    build_rows<<<dim3(NTOK / 256), 256, 0, stream>>>(topk_e, offs, cursors, row_tok, gate_row, topk_w);

    if (ws_size >= 106 * MB) {
        convert_x<<<dim3(NTOK * DDIM / (256 * 8)), 256, 0, stream>>>(x, xb);
        transpose_f32_bf16<<<dim3(4096 / 64, 1024 / 64, NEXP), 256, 0, stream>>>(w1, w1b, 1024, 4096);
        gemm1_fast<<<dim3(NTOK / 128, FDIM / 64, NEXP), 256, 0, stream>>>(xb, w1b, act, row_tok, counts, offs);
        transpose_f32_bf16<<<dim3(1024 / 64, 2048 / 64, NEXP), 256, 0, stream>>>(w2, w2b, 2048, 1024);
        gemm2_fast<<<dim3(NTOK / 128, DDIM / 128, NEXP), 256, 0, stream>>>(act, w2b, out, row_tok, gate_row, counts, offs);
    } else {
        gemm1_kernel<<<dim3(NTOK / 128, FDIM / 64, NEXP), 256, 0, stream>>>(x, w1, act, row_tok, counts, offs);
        gemm2_kernel<<<dim3(NTOK / 128, DDIM / 64, NEXP), 256, 0, stream>>>(act, w2, out, row_tok, gate_row, counts, offs);
    }
    (void)in_sizes; (void)n_in; (void)ws_size;
}

// Round 5
// 596.981 us; speedup vs baseline: 2.5994x; 1.9946x over previous
//
#include <hip/hip_runtime.h>
#include <stdint.h>

typedef unsigned short u16;
typedef __attribute__((ext_vector_type(8))) short short8;   // 8 bf16 = 4 VGPRs
typedef __attribute__((ext_vector_type(4))) float floatx4;  // MFMA accumulator

#define NTOK 4096
#define DDIM 1024
#define FDIM 2048
#define NEXP 8

__device__ __forceinline__ u16 f2bf(float f) {
    union { float f; uint32_t u; } v; v.f = f;
    uint32_t r = v.u + 0x7fff + ((v.u >> 16) & 1);  // RNE
    return (u16)(r >> 16);
}
__device__ __forceinline__ uint32_t pk2(float a, float b) {
    return (uint32_t)f2bf(a) | ((uint32_t)f2bf(b) << 16);
}
// async global->LDS, 16B per lane; LDS dest is wave-uniform base + lane*16
__device__ __forceinline__ void gl_lds16(const u16* g, u16* l) {
    __builtin_amdgcn_global_load_lds(
        (const __attribute__((address_space(1))) uint32_t*)g,
        (__attribute__((address_space(3))) uint32_t*)l, 16, 0, 0);
}

// ---------------------------------------------------------------- router
__global__ __launch_bounds__(256)
void router_kernel(const float* __restrict__ x, const float* __restrict__ rw,
                   int* __restrict__ counts, int* __restrict__ topk_e,
                   float* __restrict__ topk_w) {
    const int lane = threadIdx.x & 63;
    const int wv = threadIdx.x >> 6;
    const int tok = blockIdx.x * 4 + wv;
    const float* xr = x + (size_t)tok * DDIM;
    float acc[8];
#pragma unroll
    for (int e = 0; e < 8; ++e) acc[e] = 0.f;
#pragma unroll
    for (int it = 0; it < 4; ++it) {
        int d0 = (it * 64 + lane) * 4;
        float4 xv = *(const float4*)(xr + d0);
#pragma unroll
        for (int e = 0; e < 8; ++e) {
            float4 wv4 = *(const float4*)(rw + (size_t)e * DDIM + d0);
            acc[e] += xv.x * wv4.x + xv.y * wv4.y + xv.z * wv4.z + xv.w * wv4.w;
        }
    }
#pragma unroll
    for (int s = 32; s > 0; s >>= 1)
#pragma unroll
        for (int e = 0; e < 8; ++e) acc[e] += __shfl_down(acc[e], s);
    if (lane == 0) {
        int e0 = 0;
#pragma unroll
        for (int e = 1; e < 8; ++e) if (acc[e] > acc[e0]) e0 = e;
        int e1 = (e0 == 0) ? 1 : 0;
#pragma unroll
        for (int e = 0; e < 8; ++e) if (e != e0 && acc[e] > acc[e1]) e1 = e;
        float w0 = 1.f / (1.f + __expf(acc[e1] - acc[e0]));
        topk_e[tok * 2 + 0] = e0;
        topk_e[tok * 2 + 1] = e1;
        topk_w[tok * 2 + 0] = w0;
        topk_w[tok * 2 + 1] = 1.f - w0;
        atomicAdd(&counts[e0], 1);
        atomicAdd(&counts[e1], 1);
    }
}

// prefix sums + m-block dispatch table (kills null blocks)
__global__ void prefix_kernel(const int* __restrict__ counts, int* __restrict__ offs,
                              int* __restrict__ cursors, int* __restrict__ nmb,
                              int* __restrict__ mb_e, int* __restrict__ mb_m0) {
    if (threadIdx.x == 0) {
        int s = 0, nm = 0;
        for (int e = 0; e < NEXP; ++e) {
            offs[e] = s;
            int nb = (counts[e] + 127) >> 7;
            for (int b = 0; b < nb; ++b) { mb_e[nm] = e; mb_m0[nm] = b * 128; ++nm; }
            s += counts[e];
        }
        offs[NEXP] = s;
        *nmb = nm;
    }
    if (threadIdx.x < NEXP) cursors[threadIdx.x] = 0;
}

__global__ __launch_bounds__(256)
void build_rows(const int* __restrict__ topk_e, const int* __restrict__ offs,
                int* __restrict__ cursors, int* __restrict__ row_tok,
                float* __restrict__ gate_row, const float* __restrict__ topk_w) {
    int tok = blockIdx.x * 256 + threadIdx.x;
#pragma unroll
    for (int k = 0; k < 2; ++k) {
        int e = topk_e[tok * 2 + k];
        int slot = atomicAdd(&cursors[e], 1);
        int row = offs[e] + slot;
        row_tok[row] = tok;
        gate_row[row] = topk_w[tok * 2 + k];
    }
}

// ---------------------------------------------------------------- prep passes
__global__ __launch_bounds__(256)
void convert_x(const float* __restrict__ src, u16* __restrict__ dst) {
    size_t i = ((size_t)blockIdx.x * 256 + threadIdx.x) * 8;
    float4 a = *(const float4*)(src + i);
    float4 b = *(const float4*)(src + i + 4);
    uint4 o = { pk2(a.x, a.y), pk2(a.z, a.w), pk2(b.x, b.y), pk2(b.z, b.w) };
    *(uint4*)(dst + i) = o;
}

// per-expert [R][C] fp32 -> [C][R] bf16, 64x64 LDS tiles. grid (C/64, R/64, E)
__global__ __launch_bounds__(256)
void transpose_f32_bf16(const float* __restrict__ src, u16* __restrict__ dst,
                        int R, int C) {
    __shared__ float tile[64][65];
    size_t eo = (size_t)blockIdx.z * R * C;
    const float* S = src + eo;
    u16* D = dst + eo;
    int r0 = blockIdx.y * 64, c0 = blockIdx.x * 64;
    int t = threadIdx.x;
    int rr = t >> 4;
    int cc = (t & 15) * 4;
#pragma unroll
    for (int it = 0; it < 4; ++it) {
        int r = rr + it * 16;
        float4 v = *(const float4*)(S + (size_t)(r0 + r) * C + (c0 + cc));
        tile[cc + 0][r] = v.x; tile[cc + 1][r] = v.y;
        tile[cc + 2][r] = v.z; tile[cc + 3][r] = v.w;
    }
    __syncthreads();
#pragma unroll
    for (int it = 0; it < 2; ++it) {
        int u = it * 256 + t;
        int c = u >> 3;
        int rv = (u & 7) * 8;
        uint4 o;
        o.x = pk2(tile[c][rv + 0], tile[c][rv + 1]);
        o.y = pk2(tile[c][rv + 2], tile[c][rv + 3]);
        o.z = pk2(tile[c][rv + 4], tile[c][rv + 5]);
        o.w = pk2(tile[c][rv + 6], tile[c][rv + 7]);
        *(uint4*)(D + (size_t)(c0 + c) * R + (r0 + rv)) = o;
    }
}

// ---------------------------------------------------------------- GEMM1 + SwiGLU
// gathered xb @ w1b[e] -> act = silu(g)*h
// tile 128m x 64n (B-tile = 64 g-rows + 64 h-rows), BK=64 as 2x32 slabs.
// LDS row-major [slab][row][32]: 64B/row -> coalesced 4-lane staging,
// conflict-free b128 frag reads (row*64B + quad*16B -> uniform banks).
__global__ __launch_bounds__(256, 2)
void gemm1_fast(const u16* __restrict__ xb, const u16* __restrict__ w1b,
                u16* __restrict__ act, const int* __restrict__ row_tok,
                const int* __restrict__ counts, const int* __restrict__ offs,
                const int* __restrict__ nmb, const int* __restrict__ mb_e,
                const int* __restrict__ mb_m0) {
    const int mbid = blockIdx.x;
    if (mbid >= *nmb) return;
    const int e = mb_e[mbid];
    const int m0 = mb_m0[mbid];
    const int cnt = counts[e];
    const int off = offs[e];
    const int n0 = blockIdx.y * 64;

    __shared__ __align__(16) u16 As[2 * 128 * 32];  // [s][m][kk]
    __shared__ __align__(16) u16 Bs[2 * 128 * 32];  // [s][r][kk]; r<64: g, r>=64: h

    const int t = threadIdx.x;
    const int lane = t & 63;
    const int wv = t >> 6;
    const int quad = lane >> 4;
    const int rr = lane & 15;
    const int wm = (wv & 1) * 64;
    const int wn = (wv >> 1) * 32;

    // staging: lane group-of-4 covers one row's 32-k slab (64B contiguous)
    const int srow = wv * 32 + (lane >> 2);  // 0..31 within wave -> rows wv*32..+31
    const int scol = (lane & 3) * 8;
    const u16* arA[2];
    const u16* arB[2];
#pragma unroll
    for (int i = 0; i < 2; ++i) {
        int m = srow + i * 16 - (lane >> 2 & 16);  // rows wv*32+i*16 .. +15
        // recompute cleanly:
        m = wv * 32 + i * 16 + ((lane >> 2) & 15);
        int r = m0 + m; if (r >= cnt) r = cnt - 1;
        arA[i] = xb + (size_t)row_tok[off + r] * DDIM + scol;
        int br = wv * 32 + i * 16 + ((lane >> 2) & 15);  // 0..127
        size_t brow = (br < 64) ? ((size_t)e * 4096 + n0 + br)
                                : ((size_t)e * 4096 + 2048 + n0 + (br - 64));
        arB[i] = w1b + brow * DDIM + scol;
    }
    u16* dstA[2][2];
    u16* dstB[2][2];
#pragma unroll
    for (int s = 0; s < 2; ++s)
#pragma unroll
        for (int i = 0; i < 2; ++i) {
            dstA[s][i] = &As[(s * 128 + wv * 32 + i * 16) * 32];
            dstB[s][i] = &Bs[(s * 128 + wv * 32 + i * 16) * 32];
        }

    floatx4 accg[4][2] = {};
    floatx4 acch[4][2] = {};

    for (int k0 = 0; k0 < DDIM; k0 += 64) {
        __syncthreads();
#pragma unroll
        for (int s = 0; s < 2; ++s)
#pragma unroll
            for (int i = 0; i < 2; ++i) {
                gl_lds16(arA[i] + k0 + s * 32, dstA[s][i]);
                gl_lds16(arB[i] + k0 + s * 32, dstB[s][i]);
            }
        __syncthreads();

#pragma unroll
        for (int s = 0; s < 2; ++s) {
            short8 af[4], bg[2], bh[2];
#pragma unroll
            for (int mt = 0; mt < 4; ++mt)
                af[mt] = *(const short8*)&As[(s * 128 + wm + mt * 16 + rr) * 32 + quad * 8];
#pragma unroll
            for (int nt = 0; nt < 2; ++nt) {
                bg[nt] = *(const short8*)&Bs[(s * 128 + wn + nt * 16 + rr) * 32 + quad * 8];
                bh[nt] = *(const short8*)&Bs[(s * 128 + 64 + wn + nt * 16 + rr) * 32 + quad * 8];
            }
#pragma unroll
            for (int mt = 0; mt < 4; ++mt)
#pragma unroll
                for (int nt = 0; nt < 2; ++nt) {
                    accg[mt][nt] = __builtin_amdgcn_mfma_f32_16x16x32_bf16(af[mt], bg[nt], accg[mt][nt], 0, 0, 0);
                    acch[mt][nt] = __builtin_amdgcn_mfma_f32_16x16x32_bf16(af[mt], bh[nt], acch[mt][nt], 0, 0, 0);
                }
        }
    }
#pragma unroll
    for (int mt = 0; mt < 4; ++mt)
#pragma unroll
        for (int nt = 0; nt < 2; ++nt)
#pragma unroll
            for (int rg = 0; rg < 4; ++rg) {
                int gm = m0 + wm + mt * 16 + quad * 4 + rg;
                if (gm < cnt) {
                    float g = accg[mt][nt][rg];
                    float h = acch[mt][nt][rg];
                    float s = g / (1.f + __expf(-g));
                    act[(size_t)(off + gm) * FDIM + (n0 + wn + nt * 16 + rr)] = f2bf(s * h);
                }
            }
}

// ---------------------------------------------------------------- GEMM2 + scatter
// act @ w2b[e] ([1024][2048] bf16 n-major) -> out += gate*y (fp32 atomics)
// tile 128m x 128n, BK=64 as 2x32 slabs, same LDS scheme.
__global__ __launch_bounds__(256, 2)
void gemm2_fast(const u16* __restrict__ act, const u16* __restrict__ w2b,
                float* __restrict__ out, const int* __restrict__ row_tok,
                const float* __restrict__ gate_row, const int* __restrict__ counts,
                const int* __restrict__ offs, const int* __restrict__ nmb,
                const int* __restrict__ mb_e, const int* __restrict__ mb_m0) {
    const int mbid = blockIdx.x;
    if (mbid >= *nmb) return;
    const int e = mb_e[mbid];
    const int m0 = mb_m0[mbid];
    const int cnt = counts[e];
    const int off = offs[e];
    const int n0 = blockIdx.y * 128;

    __shared__ __align__(16) u16 As[2 * 128 * 32];
    __shared__ __align__(16) u16 Bs[2 * 128 * 32];

    const int t = threadIdx.x;
    const int lane = t & 63;
    const int wv = t >> 6;
    const int quad = lane >> 4;
    const int rr = lane & 15;
    const int wm = (wv & 1) * 64;
    const int wn = (wv >> 1) * 64;

    const int scol = (lane & 3) * 8;
    const u16* arA[2];
    const u16* arB[2];
#pragma unroll
    for (int i = 0; i < 2; ++i) {
        int m = wv * 32 + i * 16 + ((lane >> 2) & 15);
        int r = m0 + m; if (r >= cnt) r = cnt - 1;
        arA[i] = act + (size_t)(off + r) * FDIM + scol;
        arB[i] = w2b + ((size_t)e * 1024 + n0 + m) * FDIM + scol;
    }
    u16* dstA[2][2];
    u16* dstB[2][2];
#pragma unroll
    for (int s = 0; s < 2; ++s)
#pragma unroll
        for (int i = 0; i < 2; ++i) {
            dstA[s][i] = &As[(s * 128 + wv * 32 + i * 16) * 32];
            dstB[s][i] = &Bs[(s * 128 + wv * 32 + i * 16) * 32];
        }

    floatx4 acc[4][4] = {};

    for (int k0 = 0; k0 < FDIM; k0 += 64) {
        __syncthreads();
#pragma unroll
        for (int s = 0; s < 2; ++s)
#pragma unroll
            for (int i = 0; i < 2; ++i) {
                gl_lds16(arA[i] + k0 + s * 32, dstA[s][i]);
                gl_lds16(arB[i] + k0 + s * 32, dstB[s][i]);
            }
        __syncthreads();

#pragma unroll
        for (int s = 0; s < 2; ++s) {
            short8 af[4], bf[4];
#pragma unroll
            for (int mt = 0; mt < 4; ++mt)
                af[mt] = *(const short8*)&As[(s * 128 + wm + mt * 16 + rr) * 32 + quad * 8];
#pragma unroll
            for (int nt = 0; nt < 4; ++nt)
                bf[nt] = *(const short8*)&Bs[(s * 128 + wn + nt * 16 + rr) * 32 + quad * 8];
#pragma unroll
            for (int mt = 0; mt < 4; ++mt)
#pragma unroll
                for (int nt = 0; nt < 4; ++nt)
                    acc[mt][nt] = __builtin_amdgcn_mfma_f32_16x16x32_bf16(af[mt], bf[nt], acc[mt][nt], 0, 0, 0);
        }
    }
#pragma unroll
    for (int mt = 0; mt < 4; ++mt)
#pragma unroll
        for (int rg = 0; rg < 4; ++rg) {
            int gm = m0 + wm + mt * 16 + quad * 4 + rg;
            if (gm < cnt) {
                int gr = off + gm;
                float gate = gate_row[gr];
                float* orow = out + (size_t)row_tok[gr] * DDIM + n0 + wn;
#pragma unroll
                for (int nt = 0; nt < 4; ++nt)
                    atomicAdd(&orow[nt * 16 + rr], gate * acc[mt][nt][rg]);
            }
        }
}

// ---------------------------------------------------------------- launch
extern "C" void kernel_launch(void* const* d_in, const int* in_sizes, int n_in,
                              void* d_out, int out_size, void* d_ws, size_t ws_size,
                              hipStream_t stream) {
    const float* x  = (const float*)d_in[0];  // [4096][1024]
    const float* rw = (const float*)d_in[1];  // [8][1024]
    const float* w1 = (const float*)d_in[2];  // [8][1024][4096] k-major
    const float* w2 = (const float*)d_in[3];  // [8][2048][1024] k-major
    float* out = (float*)d_out;               // [4096][1024]

    char* ws = (char*)d_ws;
    const size_t MB = 1ull << 20;
    int*   counts   = (int*)(ws);
    int*   cursors  = (int*)(ws + 64);
    int*   offs     = (int*)(ws + 128);
    int*   nmb      = (int*)(ws + 192);
    int*   mb_e     = (int*)(ws + 256);   // up to 96 entries
    int*   mb_m0    = (int*)(ws + 768);
    int*   topk_e   = (int*)(ws + 2048);            // 32 KiB
    float* topk_w   = (float*)(ws + 2048 + 32768);  // 32 KiB
    int*   row_tok  = (int*)(ws + 2048 + 65536);    // 32 KiB
    float* gate_row = (float*)(ws + 2048 + 98304);  // 32 KiB
    u16*   act      = (u16*)(ws + 1 * MB);    // 32 MiB
    u16*   xb       = (u16*)(ws + 33 * MB);   // 8 MiB
    u16*   w1b      = (u16*)(ws + 41 * MB);   // 64 MiB (alive through gemm1)
    u16*   w2b      = (u16*)(ws + 41 * MB);   // 32 MiB overlay (after gemm1)

    hipMemsetAsync(counts, 0, 256, stream);
    hipMemsetAsync(out, 0, (size_t)out_size * 4, stream);
    router_kernel<<<dim3(NTOK / 4), 256, 0, stream>>>(x, rw, counts, topk_e, topk_w);
    prefix_kernel<<<1, 64, 0, stream>>>(counts, offs, cursors, nmb, mb_e, mb_m0);
    build_rows<<<dim3(NTOK / 256), 256, 0, stream>>>(topk_e, offs, cursors, row_tok, gate_row, topk_w);
    convert_x<<<dim3(NTOK * DDIM / (256 * 8)), 256, 0, stream>>>(x, xb);
    transpose_f32_bf16<<<dim3(4096 / 64, 1024 / 64, NEXP), 256, 0, stream>>>(w1, w1b, 1024, 4096);
    gemm1_fast<<<dim3(72, FDIM / 64), 256, 0, stream>>>(xb, w1b, act, row_tok, counts, offs, nmb, mb_e, mb_m0);
    transpose_f32_bf16<<<dim3(1024 / 64, 2048 / 64, NEXP), 256, 0, stream>>>(w2, w2b, 2048, 1024);
    gemm2_fast<<<dim3(72, DDIM / 128), 256, 0, stream>>>(act, w2b, out, row_tok, gate_row, counts, offs, nmb, mb_e, mb_m0);
    (void)in_sizes; (void)n_in; (void)ws_size;
}